// Round 1
// baseline (134.824 us; speedup 1.0000x reference)
//
#include <hip/hip_runtime.h>

#define F_NUM 40
#define E_DIM 32
#define P_NUM 780
#define B_NUM 2048
#define D_DIM 16
#define NPC   16
#define LN_EPS 1e-3f

static __device__ __forceinline__ int row_start(int i) { return i * (79 - i) / 2; }

// Kernel A: p[b,p] = x[b,i]' W[p] x[b,j]  -> pbuf[p][b]
// grid (32 batch-blocks, 39 pair-groups), block 256 (4 waves; wave = 64 batches, 5 pairs)
__global__ __launch_bounds__(256) void bilinear_pairs_kernel(
    const float* __restrict__ x, const float* __restrict__ W,
    float* __restrict__ pbuf) {
  const int lane = threadIdx.x & 63;
  const int wv   = threadIdx.x >> 6;
  const int b    = blockIdx.x * 64 + lane;
  const int p0   = blockIdx.y * 20 + wv * 5;

  // locate (i,j) of first pair: combinations(range(40),2) order
  int i = 0;
  while (row_start(i + 1) <= p0) ++i;
  int j = i + 1 + (p0 - row_start(i));

  const float* xb = x + (size_t)b * (F_NUM * E_DIM);

  float xi[E_DIM], xj[E_DIM];
#pragma unroll
  for (int k = 0; k < E_DIM / 4; ++k) {
    float4 v = *reinterpret_cast<const float4*>(xb + i * E_DIM + 4 * k);
    xi[4*k] = v.x; xi[4*k+1] = v.y; xi[4*k+2] = v.z; xi[4*k+3] = v.w;
  }
  int icur = i;

  for (int pp = 0; pp < 5; ++pp) {
    const int p = p0 + pp;
    if (i != icur) {
#pragma unroll
      for (int k = 0; k < E_DIM / 4; ++k) {
        float4 v = *reinterpret_cast<const float4*>(xb + i * E_DIM + 4 * k);
        xi[4*k] = v.x; xi[4*k+1] = v.y; xi[4*k+2] = v.z; xi[4*k+3] = v.w;
      }
      icur = i;
    }
#pragma unroll
    for (int k = 0; k < E_DIM / 4; ++k) {
      float4 v = *reinterpret_cast<const float4*>(xb + j * E_DIM + 4 * k);
      xj[4*k] = v.x; xj[4*k+1] = v.y; xj[4*k+2] = v.z; xj[4*k+3] = v.w;
    }
    // W row pointer is wave-uniform -> force SGPR so W reads go down the scalar pipe
    const int pu = __builtin_amdgcn_readfirstlane(p);
    const float* __restrict__ Wp = W + (size_t)pu * (E_DIM * E_DIM);

    float acc = 0.f;
#pragma unroll
    for (int e = 0; e < E_DIM; ++e) {
      float d0 = 0.f, d1 = 0.f, d2 = 0.f, d3 = 0.f;
#pragma unroll
      for (int f = 0; f < E_DIM; f += 4) {
        d0 = fmaf(Wp[e * E_DIM + f + 0], xj[f + 0], d0);
        d1 = fmaf(Wp[e * E_DIM + f + 1], xj[f + 1], d1);
        d2 = fmaf(Wp[e * E_DIM + f + 2], xj[f + 2], d2);
        d3 = fmaf(Wp[e * E_DIM + f + 3], xj[f + 3], d3);
      }
      acc = fmaf(xi[e], (d0 + d1) + (d2 + d3), acc);
    }
    pbuf[(size_t)p * B_NUM + b] = acc;  // lane-consecutive: coalesced

    ++j;
    if (j == F_NUM) { ++i; j = i + 1; }
  }
}

// Kernel B: partial h over pair-chunks. grid (8, NPC), block 256.
__global__ __launch_bounds__(256) void dense_partial_kernel(
    const float* __restrict__ pbuf, const float* __restrict__ dw,
    float* __restrict__ hpart) {
  const int b  = blockIdx.x * 256 + threadIdx.x;
  const int pc = blockIdx.y;
  const int pstart = pc * 49;
  const int pend   = min(pstart + 49, P_NUM);
  float acc[D_DIM];
#pragma unroll
  for (int d = 0; d < D_DIM; ++d) acc[d] = 0.f;
  for (int p = pstart; p < pend; ++p) {
    const float pv = pbuf[(size_t)p * B_NUM + b];          // coalesced
    const float* __restrict__ dwp = dw + p * D_DIM;        // uniform -> s_load
#pragma unroll
    for (int d = 0; d < D_DIM; ++d) acc[d] = fmaf(pv, dwp[d], acc[d]);
  }
  float* o = hpart + ((size_t)pc * B_NUM + b) * D_DIM;
#pragma unroll
  for (int d = 0; d < D_DIM; d += 4)
    *reinterpret_cast<float4*>(o + d) =
        make_float4(acc[d], acc[d + 1], acc[d + 2], acc[d + 3]);
}

// Kernel C: sum partials + bias + LayerNorm. grid 8, block 256 (thread = batch row).
__global__ __launch_bounds__(256) void reduce_ln_kernel(
    const float* __restrict__ hpart, const float* __restrict__ bias,
    const float* __restrict__ gamma, const float* __restrict__ beta,
    float* __restrict__ out) {
  const int b = blockIdx.x * 256 + threadIdx.x;
  float h[D_DIM];
#pragma unroll
  for (int d = 0; d < D_DIM; ++d) h[d] = bias[d];
  for (int pc = 0; pc < NPC; ++pc) {
    const float* hp = hpart + ((size_t)pc * B_NUM + b) * D_DIM;
#pragma unroll
    for (int d = 0; d < D_DIM; d += 4) {
      float4 v = *reinterpret_cast<const float4*>(hp + d);
      h[d] += v.x; h[d + 1] += v.y; h[d + 2] += v.z; h[d + 3] += v.w;
    }
  }
  float mu = 0.f;
#pragma unroll
  for (int d = 0; d < D_DIM; ++d) mu += h[d];
  mu *= (1.f / D_DIM);
  float var = 0.f;
#pragma unroll
  for (int d = 0; d < D_DIM; ++d) { float t = h[d] - mu; var = fmaf(t, t, var); }
  var *= (1.f / D_DIM);
  const float rs = rsqrtf(var + LN_EPS);
#pragma unroll
  for (int d = 0; d < D_DIM; ++d)
    out[(size_t)b * D_DIM + d] = (h[d] - mu) * rs * gamma[d] + beta[d];
}

extern "C" void kernel_launch(void* const* d_in, const int* in_sizes, int n_in,
                              void* d_out, int out_size, void* d_ws, size_t ws_size,
                              hipStream_t stream) {
  const float* x     = (const float*)d_in[0];
  const float* W     = (const float*)d_in[1];
  const float* dw    = (const float*)d_in[2];
  const float* db    = (const float*)d_in[3];
  const float* gamma = (const float*)d_in[4];
  const float* beta  = (const float*)d_in[5];
  float* out = (float*)d_out;

  float* pbuf  = (float*)d_ws;                                      // 780*2048*4 = 6.39 MB
  float* hpart = (float*)((char*)d_ws + (size_t)P_NUM * B_NUM * 4); // NPC*2048*16*4 = 2 MB

  dim3 gA(B_NUM / 64, 39);
  bilinear_pairs_kernel<<<gA, 256, 0, stream>>>(x, W, pbuf);

  dim3 gB(B_NUM / 256, NPC);
  dense_partial_kernel<<<gB, 256, 0, stream>>>(pbuf, dw, hpart);

  reduce_ln_kernel<<<B_NUM / 256, 256, 0, stream>>>(hpart, db, gamma, beta, out);
}

// Round 2
// 66.116 us; speedup vs baseline: 2.0392x; 2.0392x over previous
//
#include <hip/hip_runtime.h>

typedef __attribute__((ext_vector_type(8))) short bf16x8;
typedef __attribute__((ext_vector_type(4))) short bf16x4;
typedef __attribute__((ext_vector_type(4))) float f32x4;

#define B_NUM 2048
#define F_NUM 40
#define E_DIM 32
#define P_NUM 780
#define D_DIM 16
#define NPC   16
#define LN_EPS 1e-3f

// workspace layout (bytes)
#define XB_OFF 0
#define XB_BYTES (B_NUM * F_NUM * E_DIM * 2)              // 5,242,880  bf16 x
#define WF_OFF (XB_OFF + XB_BYTES)
#define WF_BYTES (P_NUM * 2 * 64 * 8 * 2)                 // 1,597,440  pre-swizzled W frags
#define PB_OFF (WF_OFF + WF_BYTES)
#define PB_BYTES (P_NUM * B_NUM * 4)                      // 6,389,760  p (fp32)
#define HP_OFF (PB_OFF + PB_BYTES)                        // hpart

static __device__ __forceinline__ unsigned short f2b(float f) {
  unsigned u = __builtin_bit_cast(unsigned, f);
  u += 0x7fffu + ((u >> 16) & 1u);        // round-to-nearest-even
  return (unsigned short)(u >> 16);
}
static __device__ __forceinline__ float b2f(unsigned short u) {
  return __builtin_bit_cast(float, (unsigned)u << 16);
}

// ---------------------------------------------------------------------------
// Prep: convert x -> bf16 (row-major) and W -> per-lane A-fragment order.
// A-frag (M=f, K=e): lane l, reg i holds A[l&15][(l>>4)*8+i] = W[(l>>4)*8+i][mt*16+(l&15)]
// grid.x = 2560 (x chunks) + 195 (4 pairs each)
__global__ __launch_bounds__(256) void prep_kernel(
    const float* __restrict__ x, const float* __restrict__ W,
    short* __restrict__ xb, short* __restrict__ wfrag) {
  if (blockIdx.x < 2560) {
    const size_t idx = ((size_t)blockIdx.x * 256 + threadIdx.x) * 4;
    float4 v = *reinterpret_cast<const float4*>(x + idx);
    bf16x4 o;
    o[0] = (short)f2b(v.x); o[1] = (short)f2b(v.y);
    o[2] = (short)f2b(v.z); o[3] = (short)f2b(v.w);
    *reinterpret_cast<bf16x4*>(xb + idx) = o;
  } else {
    const int p    = (blockIdx.x - 2560) * 4 + (threadIdx.x >> 6);
    const int lane = threadIdx.x & 63;
    const int lhi = lane >> 4, llo = lane & 15;
    const float* Wp = W + (size_t)p * (E_DIM * E_DIM);
#pragma unroll
    for (int mt = 0; mt < 2; ++mt) {
      bf16x8 v;
#pragma unroll
      for (int t = 0; t < 8; ++t)
        v[t] = (short)f2b(Wp[(lhi * 8 + t) * E_DIM + mt * 16 + llo]);
      *reinterpret_cast<bf16x8*>(wfrag + ((size_t)(p * 2 + mt) * 64 + lane) * 8) = v;
    }
  }
}

// ---------------------------------------------------------------------------
// Kernel A: p[b,p] = xi' W_p xj via MFMA.
//   D[m=f][n=b] = sum_e Wt[f,e] * xi[b,e]   (one 16x16x32 K-step, 2 mt x 4 nt)
//   then p[b] = sum_f D[f,b]*xj[b,f]: 8 lane-local FMAs + shfl_xor(16,32).
// grid (2048/256, 780/5), block 256 = 4 waves x 64 batches.
__global__ __launch_bounds__(256) void bilinear_mfma_kernel(
    const short* __restrict__ xb, const short* __restrict__ wfrag,
    float* __restrict__ pbuf) {
  const int lane = threadIdx.x & 63;
  const int wv   = threadIdx.x >> 6;
  const int bb   = blockIdx.x * 256 + wv * 64;
  const int p0   = blockIdx.y * 5;
  const int lhi = lane >> 4, llo = lane & 15;

  // locate (i,j) of pair p0 in combinations(range(40),2) order
  int i = 0;
  while ((i + 1) * (79 - (i + 1)) / 2 <= p0) ++i;
  int j = i + 1 + (p0 - i * (79 - i) / 2);

  bf16x8 bfrag[4];            // xi^T fragments (K=e contiguous per lane)
  bool need_xi = true;

  for (int pp = 0; pp < 5; ++pp) {
    const int p = p0 + pp;
    if (need_xi) {
#pragma unroll
      for (int nt = 0; nt < 4; ++nt) {
        const int b = bb + nt * 16 + llo;
        bfrag[nt] = *reinterpret_cast<const bf16x8*>(
            xb + ((size_t)b * F_NUM + i) * E_DIM + lhi * 8);
      }
      need_xi = false;
    }
    const bf16x8 afrag0 = *reinterpret_cast<const bf16x8*>(
        wfrag + ((size_t)(p * 2 + 0) * 64 + lane) * 8);
    const bf16x8 afrag1 = *reinterpret_cast<const bf16x8*>(
        wfrag + ((size_t)(p * 2 + 1) * 64 + lane) * 8);

    bf16x4 xj[4][2];
#pragma unroll
    for (int nt = 0; nt < 4; ++nt) {
      const int b = bb + nt * 16 + llo;
      const short* base = xb + ((size_t)b * F_NUM + j) * E_DIM + lhi * 4;
      xj[nt][0] = *reinterpret_cast<const bf16x4*>(base);        // f = lhi*4+r
      xj[nt][1] = *reinterpret_cast<const bf16x4*>(base + 16);   // f = 16+lhi*4+r
    }

#pragma unroll
    for (int nt = 0; nt < 4; ++nt) {
      f32x4 z = {0.f, 0.f, 0.f, 0.f};
      f32x4 acc0 = __builtin_amdgcn_mfma_f32_16x16x32_bf16(afrag0, bfrag[nt], z, 0, 0, 0);
      f32x4 acc1 = __builtin_amdgcn_mfma_f32_16x16x32_bf16(afrag1, bfrag[nt], z, 0, 0, 0);
      float s = 0.f;
#pragma unroll
      for (int r = 0; r < 4; ++r) {
        s = fmaf(acc0[r], b2f((unsigned short)xj[nt][0][r]), s);
        s = fmaf(acc1[r], b2f((unsigned short)xj[nt][1][r]), s);
      }
      s += __shfl_xor(s, 16);
      s += __shfl_xor(s, 32);
      if (lhi == 0) pbuf[(size_t)p * B_NUM + bb + nt * 16 + llo] = s;
    }

    if (++j == F_NUM) { ++i; j = i + 1; need_xi = true; }
  }
}

// ---------------------------------------------------------------------------
// Kernel B: partial h over pair-chunks. grid (8, NPC), block 256.
__global__ __launch_bounds__(256) void dense_partial_kernel(
    const float* __restrict__ pbuf, const float* __restrict__ dw,
    float* __restrict__ hpart) {
  const int b  = blockIdx.x * 256 + threadIdx.x;
  const int pc = blockIdx.y;
  const int pstart = pc * 49;
  const int pend   = min(pstart + 49, P_NUM);
  float acc[D_DIM];
#pragma unroll
  for (int d = 0; d < D_DIM; ++d) acc[d] = 0.f;
  for (int p = pstart; p < pend; ++p) {
    const float pv = pbuf[(size_t)p * B_NUM + b];
    const float* __restrict__ dwp = dw + p * D_DIM;
#pragma unroll
    for (int d = 0; d < D_DIM; ++d) acc[d] = fmaf(pv, dwp[d], acc[d]);
  }
  float* o = hpart + ((size_t)pc * B_NUM + b) * D_DIM;
#pragma unroll
  for (int d = 0; d < D_DIM; d += 4)
    *reinterpret_cast<float4*>(o + d) =
        make_float4(acc[d], acc[d + 1], acc[d + 2], acc[d + 3]);
}

// Kernel C: sum partials + bias + LayerNorm. grid 8, block 256.
__global__ __launch_bounds__(256) void reduce_ln_kernel(
    const float* __restrict__ hpart, const float* __restrict__ bias,
    const float* __restrict__ gamma, const float* __restrict__ beta,
    float* __restrict__ out) {
  const int b = blockIdx.x * 256 + threadIdx.x;
  float h[D_DIM];
#pragma unroll
  for (int d = 0; d < D_DIM; ++d) h[d] = bias[d];
  for (int pc = 0; pc < NPC; ++pc) {
    const float* hp = hpart + ((size_t)pc * B_NUM + b) * D_DIM;
#pragma unroll
    for (int d = 0; d < D_DIM; d += 4) {
      float4 v = *reinterpret_cast<const float4*>(hp + d);
      h[d] += v.x; h[d + 1] += v.y; h[d + 2] += v.z; h[d + 3] += v.w;
    }
  }
  float mu = 0.f;
#pragma unroll
  for (int d = 0; d < D_DIM; ++d) mu += h[d];
  mu *= (1.f / D_DIM);
  float var = 0.f;
#pragma unroll
  for (int d = 0; d < D_DIM; ++d) { float t = h[d] - mu; var = fmaf(t, t, var); }
  var *= (1.f / D_DIM);
  const float rs = rsqrtf(var + LN_EPS);
#pragma unroll
  for (int d = 0; d < D_DIM; ++d)
    out[(size_t)b * D_DIM + d] = (h[d] - mu) * rs * gamma[d] + beta[d];
}

extern "C" void kernel_launch(void* const* d_in, const int* in_sizes, int n_in,
                              void* d_out, int out_size, void* d_ws, size_t ws_size,
                              hipStream_t stream) {
  const float* x     = (const float*)d_in[0];
  const float* W     = (const float*)d_in[1];
  const float* dw    = (const float*)d_in[2];
  const float* db    = (const float*)d_in[3];
  const float* gamma = (const float*)d_in[4];
  const float* beta  = (const float*)d_in[5];
  float* out = (float*)d_out;

  short* xb    = (short*)((char*)d_ws + XB_OFF);
  short* wfrag = (short*)((char*)d_ws + WF_OFF);
  float* pbuf  = (float*)((char*)d_ws + PB_OFF);
  float* hpart = (float*)((char*)d_ws + HP_OFF);

  prep_kernel<<<2560 + 195, 256, 0, stream>>>(x, W, xb, wfrag);

  dim3 gA(B_NUM / 256, P_NUM / 5);
  bilinear_mfma_kernel<<<gA, 256, 0, stream>>>(xb, wfrag, pbuf);

  dim3 gB(B_NUM / 256, NPC);
  dense_partial_kernel<<<gB, 256, 0, stream>>>(pbuf, dw, hpart);

  reduce_ln_kernel<<<B_NUM / 256, 256, 0, stream>>>(hpart, db, gamma, beta, out);
}